// Round 1
// baseline (107.024 us; speedup 1.0000x reference)
//
#include <hip/hip_runtime.h>

// CustomSoftmaxExperts: softmax over last dim (64), keep values in top-5 AND >= 0.2.
//
// Algebraic identity: since softmax rows sum to 1, any value >= 0.2 is
// automatically within the top-5 (five values strictly greater than it would
// make the row sum exceed 1.2 > 1). So the mask reduces exactly to
// (softmax >= 0.2) — no top-k needed. The same identity holds for the
// reference's own softmax values, so outputs match up to fp noise.
//
// Layout: row = 64 floats = 16 float4. Each 16-lane wave segment owns one row;
// each lane loads one float4 (16 B/lane, coalesced 1 KiB per wave load).
// __shfl_xor with strides 1,2,4,8 stays within the 16-lane segment.

__global__ __launch_bounds__(256) void softmax_experts_kernel(
    const float4* __restrict__ in, float4* __restrict__ out) {
    const int tid = blockIdx.x * blockDim.x + threadIdx.x;

    float4 x = in[tid];

    // row max (segmented over 16 lanes)
    float m = fmaxf(fmaxf(x.x, x.y), fmaxf(x.z, x.w));
#pragma unroll
    for (int d = 1; d < 16; d <<= 1)
        m = fmaxf(m, __shfl_xor(m, d));

    // exp(x - max)
    float4 e;
    e.x = __expf(x.x - m);
    e.y = __expf(x.y - m);
    e.z = __expf(x.z - m);
    e.w = __expf(x.w - m);

    // row sum
    float s = (e.x + e.y) + (e.z + e.w);
#pragma unroll
    for (int d = 1; d < 16; d <<= 1)
        s += __shfl_xor(s, d);

    const float r = 1.0f / s;

    float4 v;
    v.x = e.x * r;
    v.y = e.y * r;
    v.z = e.z * r;
    v.w = e.w * r;

    v.x = (v.x >= 0.2f) ? v.x : 0.0f;
    v.y = (v.y >= 0.2f) ? v.y : 0.0f;
    v.z = (v.z >= 0.2f) ? v.z : 0.0f;
    v.w = (v.w >= 0.2f) ? v.w : 0.0f;

    out[tid] = v;
}

extern "C" void kernel_launch(void* const* d_in, const int* in_sizes, int n_in,
                              void* d_out, int out_size, void* d_ws, size_t ws_size,
                              hipStream_t stream) {
    const float4* in = (const float4*)d_in[0];
    float4* out = (float4*)d_out;

    const int n4 = in_sizes[0] / 4;        // 16,777,216 / 4 = 4,194,304 float4s
    const int block = 256;
    const int grid = n4 / block;           // 16,384 blocks (exact multiple)

    softmax_experts_kernel<<<grid, block, 0, stream>>>(in, out);
}

// Round 3
// 102.213 us; speedup vs baseline: 1.0471x; 1.0471x over previous
//
#include <hip/hip_runtime.h>

// CustomSoftmaxExperts: softmax over last dim (64), keep values in top-5 AND >= 0.2.
//
// Algebraic identity: softmax rows sum to 1, so any value >= 0.2 is
// automatically within the top-5 (five values strictly greater would push the
// row sum past 1.2 > 1). The mask reduces exactly to (softmax >= 0.2) — no
// top-k needed. Same identity holds on the reference's own softmax values.
//
// Layout: row = 64 floats = 16 float4. Each 16-lane wave segment owns one row;
// each lane loads one float4 (16 B/lane, coalesced 1 KiB per wave load).
// __shfl_xor strides 1,2,4,8 stay within the 16-lane segment.
//
// NOTE: arithmetic path (max-subtract, sum tree order) is bit-exact vs the
// numpy reference (absmax 0.0 in R1) — do NOT reorder it; a ulp shift could
// flip an element across the 0.2 threshold (absmax would jump to ~0.2).
//
// R3 change: non-temporal store via native clang vector type (HIP float4 is a
// class type that __builtin_nontemporal_store rejects). Output is write-once,
// never re-read — NT store avoids L3 write-allocate pollution so the
// (restore-warmed) input stays L3-resident.

typedef float nfloat4 __attribute__((ext_vector_type(4)));

__global__ __launch_bounds__(256) void softmax_experts_kernel(
    const float4* __restrict__ in, nfloat4* __restrict__ out) {
    const int tid = blockIdx.x * blockDim.x + threadIdx.x;

    float4 x = in[tid];

    // row max (segmented over 16 lanes)
    float m = fmaxf(fmaxf(x.x, x.y), fmaxf(x.z, x.w));
#pragma unroll
    for (int d = 1; d < 16; d <<= 1)
        m = fmaxf(m, __shfl_xor(m, d));

    // exp(x - max)
    float4 e;
    e.x = __expf(x.x - m);
    e.y = __expf(x.y - m);
    e.z = __expf(x.z - m);
    e.w = __expf(x.w - m);

    // row sum (keep this exact tree order — bit-exact vs reference)
    float s = (e.x + e.y) + (e.z + e.w);
#pragma unroll
    for (int d = 1; d < 16; d <<= 1)
        s += __shfl_xor(s, d);

    const float r = 1.0f / s;

    nfloat4 v;
    v.x = e.x * r;
    v.y = e.y * r;
    v.z = e.z * r;
    v.w = e.w * r;

    v.x = (v.x >= 0.2f) ? v.x : 0.0f;
    v.y = (v.y >= 0.2f) ? v.y : 0.0f;
    v.z = (v.z >= 0.2f) ? v.z : 0.0f;
    v.w = (v.w >= 0.2f) ? v.w : 0.0f;

    __builtin_nontemporal_store(v, &out[tid]);
}

extern "C" void kernel_launch(void* const* d_in, const int* in_sizes, int n_in,
                              void* d_out, int out_size, void* d_ws, size_t ws_size,
                              hipStream_t stream) {
    const float4* in = (const float4*)d_in[0];
    nfloat4* out = (nfloat4*)d_out;

    const int n4 = in_sizes[0] / 4;        // 16,777,216 / 4 = 4,194,304 float4s
    const int block = 256;
    const int grid = n4 / block;           // 16,384 blocks (exact multiple)

    softmax_experts_kernel<<<grid, block, 0, stream>>>(in, out);
}